// Round 1
// baseline (161.193 us; speedup 1.0000x reference)
//
#include <hip/hip_runtime.h>
#include <hip/hip_bf16.h>
#include <stdint.h>

#define B_  8
#define T_  2048
#define D_  768
#define HD_ 64
#define M_  (B_ * T_)   // 16384

typedef short s16x8 __attribute__((ext_vector_type(8)));
typedef float f32x4 __attribute__((ext_vector_type(4)));

union Frag {
    uint4 u;
    s16x8 h;
};

__device__ __forceinline__ unsigned short f2bf(float f) {
    unsigned u = __builtin_bit_cast(unsigned, f);
    u += 0x7FFFu + ((u >> 16) & 1u);            // RNE
    return (unsigned short)(u >> 16);
}
__device__ __forceinline__ unsigned pack_bf16x2(float lo, float hi) {
    return (unsigned)f2bf(lo) | ((unsigned)f2bf(hi) << 16);
}

// ---------------------------------------------------------------------------
// Kernel 1: W^T (bf16) prep.  wt[(mat*64+n)][k] = W_mat[k][n] * (mat==0 ? 1/8*log2e : 1)
// ---------------------------------------------------------------------------
__global__ __launch_bounds__(256) void prep_wt(const float* __restrict__ Wq,
                                               const float* __restrict__ Wk,
                                               const float* __restrict__ Wv,
                                               unsigned short* __restrict__ wt) {
    int rowid = blockIdx.x;              // 0..191
    int mat = rowid >> 6, n = rowid & 63;
    const float* W = (mat == 0) ? Wq : (mat == 1) ? Wk : Wv;
    float s = (mat == 0) ? 0.18033688011112042f : 1.0f;  // 0.125 * log2(e)
    for (int k = threadIdx.x; k < D_; k += 256)
        wt[(size_t)rowid * D_ + k] = f2bf(W[(size_t)k * HD_ + n] * s);
}

// ---------------------------------------------------------------------------
// Kernel 2: QKV projection.  out[m][n] = x[m][:] . W[:][n], MFMA 16x16x32 bf16.
// Block = 256 thr (4 waves); wave w owns 16 rows (m0 = blk*64 + w*16), all 12 n-blocks.
// A-frag: 8 fp32 from x, cvt->bf16.  B-frag: 16B from wt (W^T rows, contiguous K).
// ---------------------------------------------------------------------------
__global__ __launch_bounds__(256) void qkv_proj(const float* __restrict__ x,
                                                const unsigned short* __restrict__ wt,
                                                unsigned short* __restrict__ qo,
                                                unsigned short* __restrict__ ko,
                                                unsigned short* __restrict__ vo) {
    int w = threadIdx.x >> 6, lane = threadIdx.x & 63;
    int g = lane >> 4, t = lane & 15;
    int m0 = blockIdx.x * 64 + w * 16;
    f32x4 acc[12];
#pragma unroll
    for (int i = 0; i < 12; i++) acc[i] = (f32x4){0.f, 0.f, 0.f, 0.f};
    const float* xp = x + (size_t)(m0 + t) * D_ + g * 8;
    const unsigned short* wp = wt + (size_t)t * D_ + g * 8;
    for (int k0 = 0; k0 < D_; k0 += 32) {
        float4 a0 = *(const float4*)(xp + k0);
        float4 a1 = *(const float4*)(xp + k0 + 4);
        Frag a;
        a.u.x = pack_bf16x2(a0.x, a0.y);
        a.u.y = pack_bf16x2(a0.z, a0.w);
        a.u.z = pack_bf16x2(a1.x, a1.y);
        a.u.w = pack_bf16x2(a1.z, a1.w);
#pragma unroll
        for (int nb = 0; nb < 12; nb++) {
            Frag b;
            b.u = *(const uint4*)(wp + (size_t)nb * 16 * D_ + k0);
            acc[nb] = __builtin_amdgcn_mfma_f32_16x16x32_bf16(a.h, b.h, acc[nb], 0, 0, 0);
        }
    }
#pragma unroll
    for (int nb = 0; nb < 12; nb++) {
        unsigned short* dst = (nb < 4) ? qo : (nb < 8) ? ko : vo;
        int col = (nb & 3) * 16 + t;
#pragma unroll
        for (int r = 0; r < 4; r++) {
            int row = m0 + g * 4 + r;
            dst[(size_t)row * HD_ + col] = f2bf(acc[nb][r]);
        }
    }
}

// ---------------------------------------------------------------------------
// Kernel 3: causal flash attention, swapped QK^T.
// Block = 128 thr (2 waves); wave w owns 16 q rows.  QBLK=32, KBLK=32.
// st[kb][r]: key = kt*32 + kb*16 + g*4 + r, q = t (lane&15).
// PV: O^T = V^T . P^T  (A = Vt rows, B = P^T built in-register via shfl).
// ---------------------------------------------------------------------------
__global__ __launch_bounds__(128) void attn(const unsigned short* __restrict__ qw,
                                            const unsigned short* __restrict__ kw,
                                            const unsigned short* __restrict__ vw,
                                            float* __restrict__ out) {
    __shared__ uint4 Ks[256];  // [key 0..31][slot 0..7], slot = 16B (8 bf16 of d), XOR-swizzled
    __shared__ uint4 Vt[256];  // [d 0..63][slot 0..3],  slot = 8 keys, XOR-swizzled

    int j = blockIdx.x;
    int b = j >> 6, i = j & 63;
    int qb = (i & 1) ? (63 - (i >> 1)) : (i >> 1);   // pair heavy+light blocks
    int q0 = qb * 32;
    int w = threadIdx.x >> 6, lane = threadIdx.x & 63;
    int g = lane >> 4, t = lane & 15;
    int tid = threadIdx.x;
    int qrow = q0 + w * 16 + t;          // this lane's q (MFMA col)
    size_t bbase = (size_t)b * T_;

    Frag qf[2];
#pragma unroll
    for (int c = 0; c < 2; c++)
        qf[c].u = *(const uint4*)(qw + (bbase + qrow) * HD_ + c * 32 + g * 8);

    f32x4 o[4];
#pragma unroll
    for (int d = 0; d < 4; d++) o[d] = (f32x4){0.f, 0.f, 0.f, 0.f};
    float m = -1e30f, l = 0.0f;

    for (int kt = 0; kt <= qb; kt++) {
        int kv0 = kt * 32;
        __syncthreads();
        {   // stage K tile [32 keys][64 d] bf16, swizzled: slot ^= (key&7)
            int key = tid >> 2, s2 = tid & 3;
            const uint4* src = (const uint4*)(kw + (bbase + kv0 + key) * HD_);
#pragma unroll
            for (int ii = 0; ii < 2; ii++) {
                int sl = s2 * 2 + ii;
                Ks[key * 8 + (sl ^ (key & 7))] = src[sl];
            }
        }
        {   // stage V transposed: Vt[d][key], swizzled: slot ^= (d&3)^((d>>2)&3)
            int d = tid >> 1, kh = tid & 1;
            const unsigned short* vs = vw + (bbase + kv0 + kh * 16) * HD_ + d;
            unsigned short e[16];
#pragma unroll
            for (int jj = 0; jj < 16; jj++) e[jj] = vs[(size_t)jj * HD_];
            uint4 lo, hi;
            lo.x = e[0] | (e[1] << 16);  lo.y = e[2] | (e[3] << 16);
            lo.z = e[4] | (e[5] << 16);  lo.w = e[6] | (e[7] << 16);
            hi.x = e[8] | (e[9] << 16);  hi.y = e[10] | (e[11] << 16);
            hi.z = e[12] | (e[13] << 16); hi.w = e[14] | (e[15] << 16);
            int swz = (d & 3) ^ ((d >> 2) & 3);
            Vt[d * 4 + ((kh * 2 + 0) ^ swz)] = lo;
            Vt[d * 4 + ((kh * 2 + 1) ^ swz)] = hi;
        }
        __syncthreads();

        // S^T = K . Q^T  (scale & log2e pre-folded into q)
        f32x4 st[2];
        st[0] = (f32x4){0.f, 0.f, 0.f, 0.f};
        st[1] = (f32x4){0.f, 0.f, 0.f, 0.f};
#pragma unroll
        for (int kb = 0; kb < 2; kb++) {
            int key = kb * 16 + t;
#pragma unroll
            for (int c = 0; c < 2; c++) {
                Frag a;
                a.u = Ks[key * 8 + ((c * 4 + g) ^ (key & 7))];
                st[kb] = __builtin_amdgcn_mfma_f32_16x16x32_bf16(a.h, qf[c].h, st[kb], 0, 0, 0);
            }
        }
        // causal mask (only tiles overlapping the diagonal of this wave)
        if (kv0 + 31 > q0 + w * 16) {
#pragma unroll
            for (int kb = 0; kb < 2; kb++)
#pragma unroll
                for (int r = 0; r < 4; r++)
                    if (kv0 + kb * 16 + g * 4 + r > qrow) st[kb][r] = -1e30f;
        }
        // online softmax over keys (spread across 8 regs x 4 lane-groups)
        float ml = fmaxf(fmaxf(fmaxf(st[0][0], st[0][1]), fmaxf(st[0][2], st[0][3])),
                         fmaxf(fmaxf(st[1][0], st[1][1]), fmaxf(st[1][2], st[1][3])));
        ml = fmaxf(ml, __shfl_xor(ml, 16));
        ml = fmaxf(ml, __shfl_xor(ml, 32));
        float mn = fmaxf(m, ml);
        float alpha = exp2f(m - mn);
        m = mn;
        float p[2][4];
        float ssum = 0.f;
#pragma unroll
        for (int kb = 0; kb < 2; kb++)
#pragma unroll
            for (int r = 0; r < 4; r++) {
                p[kb][r] = exp2f(st[kb][r] - m);
                ssum += p[kb][r];
            }
        ssum += __shfl_xor(ssum, 16);
        ssum += __shfl_xor(ssum, 32);
        l = l * alpha + ssum;
#pragma unroll
        for (int d = 0; d < 4; d++) o[d] *= alpha;

        // pack P -> bf16 pairs; regroup quads across lane-groups to B-frag layout
        unsigned pk0[2], pk1[2];
        pk0[0] = pack_bf16x2(p[0][0], p[0][1]); pk0[1] = pack_bf16x2(p[0][2], p[0][3]);
        pk1[0] = pack_bf16x2(p[1][0], p[1][1]); pk1[1] = pack_bf16x2(p[1][2], p[1][3]);
        Frag pf;
        unsigned pw[4];
#pragma unroll
        for (int w2 = 0; w2 < 4; w2++) {
            int src = ((g & 1) * 2 + (w2 >> 1)) * 16 + t;
            unsigned vlo = (unsigned)__shfl((int)pk0[w2 & 1], src, 64);
            unsigned vhi = (unsigned)__shfl((int)pk1[w2 & 1], src, 64);
            pw[w2] = (lane < 32) ? vlo : vhi;
        }
        pf.u.x = pw[0]; pf.u.y = pw[1]; pf.u.z = pw[2]; pf.u.w = pw[3];

        // O^T += V^T . P^T
#pragma unroll
        for (int db = 0; db < 4; db++) {
            int d = db * 16 + t;
            Frag a;
            a.u = Vt[d * 4 + (g ^ (d & 3) ^ ((d >> 2) & 3))];
            o[db] = __builtin_amdgcn_mfma_f32_16x16x32_bf16(a.h, pf.h, o[db], 0, 0, 0);
        }
    }

    float inv = 1.0f / l;
    float* op = out + (bbase + qrow) * HD_;
#pragma unroll
    for (int db = 0; db < 4; db++)
#pragma unroll
        for (int r = 0; r < 4; r++)
            op[db * 16 + g * 4 + r] = o[db][r] * inv;
}

// ---------------------------------------------------------------------------
extern "C" void kernel_launch(void* const* d_in, const int* in_sizes, int n_in,
                              void* d_out, int out_size, void* d_ws, size_t ws_size,
                              hipStream_t stream) {
    const float* x  = (const float*)d_in[0];
    const float* Wq = (const float*)d_in[1];
    const float* Wk = (const float*)d_in[2];
    const float* Wv = (const float*)d_in[3];
    char* ws = (char*)d_ws;
    unsigned short* wt = (unsigned short*)ws;                         // 294912 B
    unsigned short* qw = (unsigned short*)(ws + 294912);              // 2 MB
    unsigned short* kw = (unsigned short*)(ws + 294912 + 2097152);    // 2 MB
    unsigned short* vw = (unsigned short*)(ws + 294912 + 4194304);    // 2 MB
    float* out = (float*)d_out;

    hipLaunchKernelGGL(prep_wt, dim3(192), dim3(256), 0, stream, Wq, Wk, Wv, wt);
    hipLaunchKernelGGL(qkv_proj, dim3(M_ / 64), dim3(256), 0, stream, x, wt, qw, kw, vw);
    hipLaunchKernelGGL(attn, dim3(512), dim3(128), 0, stream, qw, kw, vw, out);
}

// Round 2
// 124.616 us; speedup vs baseline: 1.2935x; 1.2935x over previous
//
#include <hip/hip_runtime.h>
#include <hip/hip_bf16.h>
#include <stdint.h>

#define B_  8
#define T_  2048
#define D_  768
#define HD_ 64
#define M_  (B_ * T_)   // 16384

typedef short s16x8 __attribute__((ext_vector_type(8)));
typedef float f32x4 __attribute__((ext_vector_type(4)));

union Frag {
    uint4 u;
    s16x8 h;
};

__device__ __forceinline__ unsigned short f2bf(float f) {
    unsigned u = __builtin_bit_cast(unsigned, f);
    u += 0x7FFFu + ((u >> 16) & 1u);            // RNE
    return (unsigned short)(u >> 16);
}
__device__ __forceinline__ unsigned pack_bf16x2(float lo, float hi) {
    return (unsigned)f2bf(lo) | ((unsigned)f2bf(hi) << 16);
}

// ---------------------------------------------------------------------------
// Kernel 1: W^T (bf16) prep.  wt[(mat*64+n)][k] = W_mat[k][n] * (mat==0 ? 1/8*log2e : 1)
// ---------------------------------------------------------------------------
__global__ __launch_bounds__(256) void prep_wt(const float* __restrict__ Wq,
                                               const float* __restrict__ Wk,
                                               const float* __restrict__ Wv,
                                               unsigned short* __restrict__ wt) {
    int rowid = blockIdx.x;              // 0..191
    int mat = rowid >> 6, n = rowid & 63;
    const float* W = (mat == 0) ? Wq : (mat == 1) ? Wk : Wv;
    float s = (mat == 0) ? 0.18033688011112042f : 1.0f;  // 0.125 * log2(e)
    for (int k = threadIdx.x; k < D_; k += 256)
        wt[(size_t)rowid * D_ + k] = f2bf(W[(size_t)k * HD_ + n] * s);
}

// ---------------------------------------------------------------------------
// Kernel 2: QKV projection, nb-split across waves for occupancy.
// Grid 1024 blocks x 256 thr (4 waves). Block owns 16 rows; wave w computes
// n-blocks {3w, 3w+1, 3w+2} over full K (redundant x reads are L1/L2 hits).
// V output is written TRANSPOSED: vt[b][d][t]  (so attn can load V^T frags
// with direct 16B reads).
// ---------------------------------------------------------------------------
__global__ __launch_bounds__(256, 4) void qkv_proj(const float* __restrict__ x,
                                                   const unsigned short* __restrict__ wt,
                                                   unsigned short* __restrict__ qo,
                                                   unsigned short* __restrict__ ko,
                                                   unsigned short* __restrict__ vt) {
    int w = threadIdx.x >> 6, lane = threadIdx.x & 63;
    int g = lane >> 4, t = lane & 15;
    int m0 = blockIdx.x * 16;
    f32x4 acc[3];
#pragma unroll
    for (int j = 0; j < 3; j++) acc[j] = (f32x4){0.f, 0.f, 0.f, 0.f};
    const float* xp = x + (size_t)(m0 + t) * D_ + g * 8;
    const unsigned short* wp = wt + (size_t)(w * 48 + t) * D_ + g * 8;
    for (int k0 = 0; k0 < D_; k0 += 32) {
        float4 a0 = *(const float4*)(xp + k0);
        float4 a1 = *(const float4*)(xp + k0 + 4);
        Frag a;
        a.u.x = pack_bf16x2(a0.x, a0.y);
        a.u.y = pack_bf16x2(a0.z, a0.w);
        a.u.z = pack_bf16x2(a1.x, a1.y);
        a.u.w = pack_bf16x2(a1.z, a1.w);
#pragma unroll
        for (int j = 0; j < 3; j++) {
            Frag bfr;
            bfr.u = *(const uint4*)(wp + (size_t)j * 16 * D_ + k0);
            acc[j] = __builtin_amdgcn_mfma_f32_16x16x32_bf16(a.h, bfr.h, acc[j], 0, 0, 0);
        }
    }
#pragma unroll
    for (int j = 0; j < 3; j++) {
        int nb = w * 3 + j;
        int col = (nb & 3) * 16 + t;
        if (nb < 8) {
            unsigned short* dst = (nb < 4) ? qo : ko;
#pragma unroll
            for (int r = 0; r < 4; r++)
                dst[(size_t)(m0 + g * 4 + r) * HD_ + col] = f2bf(acc[j][r]);
        } else {
            int bb = m0 >> 11;
            int trow = (m0 & 2047) + g * 4;
            uint2 pk;
            pk.x = pack_bf16x2(acc[j][0], acc[j][1]);
            pk.y = pack_bf16x2(acc[j][2], acc[j][3]);
            *(uint2*)(vt + (((size_t)(bb * HD_ + col)) << 11) + trow) = pk;
        }
    }
}

// ---------------------------------------------------------------------------
// Kernel 3: causal flash attention, no LDS staging (K/V are L2-resident),
// flash-decode K-split: 4 waves per block over the same 16 q-rows, wave ks
// handles kt = ks, ks+4, ... ; online-softmax states merged via LDS at end.
// ---------------------------------------------------------------------------
__global__ __launch_bounds__(256, 4) void attn(const unsigned short* __restrict__ qw,
                                               const unsigned short* __restrict__ kw,
                                               const unsigned short* __restrict__ vt,
                                               float* __restrict__ out) {
    __shared__ float Lm[4][64];
    __shared__ float Ll[4][64];
    __shared__ float Lo[4][64][16];

    int blk = blockIdx.x;
    int b = blk >> 7, i = blk & 127;
    int qt = (i & 1) ? (127 - (i >> 1)) : (i >> 1);   // pair heavy+light q-tiles
    int q0 = qt * 16;
    int ks = threadIdx.x >> 6, lane = threadIdx.x & 63;
    int g = lane >> 4, t = lane & 15;
    size_t bbase = (size_t)b * T_;
    int qrow = q0 + t;

    Frag qf[2];
#pragma unroll
    for (int c = 0; c < 2; c++)
        qf[c].u = *(const uint4*)(qw + (bbase + qrow) * HD_ + c * 32 + g * 8);

    f32x4 o[4];
#pragma unroll
    for (int d = 0; d < 4; d++) o[d] = (f32x4){0.f, 0.f, 0.f, 0.f};
    float m = -1e30f, l = 0.0f;

    int n_kt = (qt >> 1) + 1;   // ceil((qt+1)/2) 32-key tiles
    const unsigned short* kp = kw + bbase * HD_;
    const unsigned short* vp = vt + ((size_t)(b * HD_) << 11);

    for (int kt = ks; kt < n_kt; kt += 4) {
        int kv0 = kt * 32;
        // direct L2 loads: K A-frags and V^T A-frags
        Frag ka[2][2], va[4];
#pragma unroll
        for (int kb = 0; kb < 2; kb++)
#pragma unroll
            for (int c = 0; c < 2; c++)
                ka[kb][c].u = *(const uint4*)(kp + (size_t)(kv0 + kb * 16 + t) * HD_ + c * 32 + g * 8);
#pragma unroll
        for (int db = 0; db < 4; db++)
            va[db].u = *(const uint4*)(vp + (((size_t)(db * 16 + t)) << 11) + kv0 + g * 8);

        // S^T = K . Q^T  (scale & log2e pre-folded into q)
        f32x4 st[2];
        st[0] = (f32x4){0.f, 0.f, 0.f, 0.f};
        st[1] = (f32x4){0.f, 0.f, 0.f, 0.f};
        __builtin_amdgcn_s_setprio(1);
#pragma unroll
        for (int kb = 0; kb < 2; kb++)
#pragma unroll
            for (int c = 0; c < 2; c++)
                st[kb] = __builtin_amdgcn_mfma_f32_16x16x32_bf16(ka[kb][c].h, qf[c].h, st[kb], 0, 0, 0);
        __builtin_amdgcn_s_setprio(0);

        // causal mask (only tiles overlapping the diagonal)
        if (kv0 + 31 > q0) {
#pragma unroll
            for (int kb = 0; kb < 2; kb++)
#pragma unroll
                for (int r = 0; r < 4; r++)
                    if (kv0 + kb * 16 + g * 4 + r > qrow) st[kb][r] = -1e30f;
        }
        // online softmax (keys spread across 8 regs x 4 lane-groups)
        float ml = fmaxf(fmaxf(fmaxf(st[0][0], st[0][1]), fmaxf(st[0][2], st[0][3])),
                         fmaxf(fmaxf(st[1][0], st[1][1]), fmaxf(st[1][2], st[1][3])));
        ml = fmaxf(ml, __shfl_xor(ml, 16));
        ml = fmaxf(ml, __shfl_xor(ml, 32));
        float mn = fmaxf(m, ml);
        float alpha = exp2f(m - mn);
        m = mn;
        float p[2][4];
        float ssum = 0.f;
#pragma unroll
        for (int kb = 0; kb < 2; kb++)
#pragma unroll
            for (int r = 0; r < 4; r++) {
                p[kb][r] = exp2f(st[kb][r] - m);
                ssum += p[kb][r];
            }
        ssum += __shfl_xor(ssum, 16);
        ssum += __shfl_xor(ssum, 32);
        l = l * alpha + ssum;
#pragma unroll
        for (int d = 0; d < 4; d++) o[d] *= alpha;

        // pack P -> bf16; regroup quads across lane-groups to B-frag layout
        unsigned pk0[2], pk1[2];
        pk0[0] = pack_bf16x2(p[0][0], p[0][1]); pk0[1] = pack_bf16x2(p[0][2], p[0][3]);
        pk1[0] = pack_bf16x2(p[1][0], p[1][1]); pk1[1] = pack_bf16x2(p[1][2], p[1][3]);
        Frag pf;
        unsigned pw[4];
#pragma unroll
        for (int w2 = 0; w2 < 4; w2++) {
            int src = ((g & 1) * 2 + (w2 >> 1)) * 16 + t;
            unsigned vlo = (unsigned)__shfl((int)pk0[w2 & 1], src, 64);
            unsigned vhi = (unsigned)__shfl((int)pk1[w2 & 1], src, 64);
            pw[w2] = (lane < 32) ? vlo : vhi;
        }
        pf.u.x = pw[0]; pf.u.y = pw[1]; pf.u.z = pw[2]; pf.u.w = pw[3];

        // O^T += V^T . P^T
        __builtin_amdgcn_s_setprio(1);
#pragma unroll
        for (int db = 0; db < 4; db++)
            o[db] = __builtin_amdgcn_mfma_f32_16x16x32_bf16(va[db].h, pf.h, o[db], 0, 0, 0);
        __builtin_amdgcn_s_setprio(0);
    }

    // merge the 4 waves' online-softmax states
    Lm[ks][lane] = m;
    Ll[ks][lane] = l;
#pragma unroll
    for (int db = 0; db < 4; db++)
#pragma unroll
        for (int r = 0; r < 4; r++) Lo[ks][lane][db * 4 + r] = o[db][r];
    __syncthreads();
    if (ks == 0) {
        float mA = Lm[0][lane], mB = Lm[1][lane], mC = Lm[2][lane], mD = Lm[3][lane];
        float ms = fmaxf(fmaxf(mA, mB), fmaxf(mC, mD));
        float e0 = exp2f(mA - ms), e1 = exp2f(mB - ms), e2 = exp2f(mC - ms), e3 = exp2f(mD - ms);
        float ls = Ll[0][lane] * e0 + Ll[1][lane] * e1 + Ll[2][lane] * e2 + Ll[3][lane] * e3;
        float inv = 1.0f / ls;
        float* op = out + (bbase + qrow) * HD_;
#pragma unroll
        for (int db = 0; db < 4; db++)
#pragma unroll
            for (int r = 0; r < 4; r++) {
                int idx = db * 4 + r;
                float s = Lo[0][lane][idx] * e0 + Lo[1][lane][idx] * e1 +
                          Lo[2][lane][idx] * e2 + Lo[3][lane][idx] * e3;
                op[db * 16 + g * 4 + r] = s * inv;
            }
    }
}

// ---------------------------------------------------------------------------
extern "C" void kernel_launch(void* const* d_in, const int* in_sizes, int n_in,
                              void* d_out, int out_size, void* d_ws, size_t ws_size,
                              hipStream_t stream) {
    const float* x  = (const float*)d_in[0];
    const float* Wq = (const float*)d_in[1];
    const float* Wk = (const float*)d_in[2];
    const float* Wv = (const float*)d_in[3];
    char* ws = (char*)d_ws;
    unsigned short* wt = (unsigned short*)ws;                         // 294912 B
    unsigned short* qw = (unsigned short*)(ws + 294912);              // 2 MB
    unsigned short* kw = (unsigned short*)(ws + 294912 + 2097152);    // 2 MB
    unsigned short* vt = (unsigned short*)(ws + 294912 + 4194304);    // 2 MB, [B][HD][T]
    float* out = (float*)d_out;

    hipLaunchKernelGGL(prep_wt, dim3(192), dim3(256), 0, stream, Wq, Wk, Wv, wt);
    hipLaunchKernelGGL(qkv_proj, dim3(M_ / 16), dim3(256), 0, stream, x, wt, qw, kw, vt);
    hipLaunchKernelGGL(attn, dim3(1024), dim3(256), 0, stream, qw, kw, vt, out);
}